// Round 5
// baseline (553.028 us; speedup 1.0000x reference)
//
#include <hip/hip_runtime.h>

#define N_NODES 100000
#define N_EDGES 6400000
#define IN_CH   128
#define HID     32

#define BKT_SHIFT 9
#define BKT_MASK  511
#define BKT_SZ    512
#define NBKT      196           // ceil(100000/512)
#define NBLK      1024          // histogram/scatter tiles
#define TILE      6250          // 6.4M / 1024 exactly
#define NCHUNK    4
#define CBASE     25000         // nodes per source chunk (3.2 MB of features)

// ---------- ws layout (bytes) ----------
// region A [0, 25.6M): ebuf during build; then hs | hs2(acc) after k_sort2
#define O_EBUF 0u
#define O_HS   0u
#define O_HS2  12800000u
// region B: ghist+cursors during build; csr16 (12.8MB) overlays after scatter
#define O_GH   25600000u        // 1024*196*4 = 802,816
#define O_CUR  26402816u        // 802,816 (dead after k_scatter)
#define O_CSR  25600000u        // ushort[6.4M] = 12,800,000 -> ends 38.4M
// small persistent region
#define O_ROWS4 38400000u       // int[4][100000] = 1,600,000
#define O_CNT4  40000000u       // int[4][100000] = 1,600,000
#define O_DINV  41600000u       // 400,000
#define O_BST   42000000u       // (NBKT+1)*4
#define O_BTOT  42002048u       // NBKT*4
#define O_FLAG  42004096u       // 4
// total ~42 MB (< 52.4 MB proven)

// Detect whether edge_index buffer is int64 (high words all zero) or int32.
__global__ void k_detect(const unsigned int* e, int* flag) {
    __shared__ int any;
    if (threadIdx.x == 0) any = 0;
    __syncthreads();
    int acc = 0;
    for (int i = threadIdx.x; i < 4096; i += 256)
        acc |= (e[2 * i + 1] != 0u);
    if (acc) atomicOr(&any, 1);
    __syncthreads();
    if (threadIdx.x == 0) *flag = any ? 0 : 1;   // 1 => int64
}

__device__ __forceinline__ int eload(const int* e, int is64, long long idx) {
    return is64 ? ((const int2*)e)[idx].x : e[(size_t)idx];
}

// Per-tile histogram over destination buckets (LDS int atomics only).
__global__ void k_hist(const int* e, const int* flag, int* ghist) {
    __shared__ int h[NBKT];
    for (int i = threadIdx.x; i < NBKT; i += 256) h[i] = 0;
    __syncthreads();
    int is64 = *flag;
    long long base = (long long)blockIdx.x * TILE;
    for (int k = threadIdx.x; k < TILE; k += 256) {
        int dst = eload(e, is64, (long long)N_EDGES + base + k);
        atomicAdd(&h[dst >> BKT_SHIFT], 1);
    }
    __syncthreads();
    int* g = ghist + blockIdx.x * NBKT;
    for (int i = threadIdx.x; i < NBKT; i += 256) g[i] = h[i];
}

__global__ void k_scan1(const int* __restrict__ ghist, int* __restrict__ btot) {
    int j = blockIdx.x * 256 + threadIdx.x;
    if (j >= NBKT) return;
    int t = 0;
    for (int blk = 0; blk < NBLK; ++blk) t += ghist[blk * NBKT + j];
    btot[j] = t;
}

__global__ void k_scan2(const int* __restrict__ btot, int* __restrict__ bstart) {
    __shared__ int s[1024];
    int t = threadIdx.x;
    int v = (t < NBKT) ? btot[t] : 0;
    s[t] = v;
    __syncthreads();
    for (int off = 1; off < 1024; off <<= 1) {
        int u = (t >= off) ? s[t - off] : 0;
        __syncthreads();
        s[t] += u;
        __syncthreads();
    }
    if (t < NBKT) bstart[t] = s[t] - v;
    if (t == 0) bstart[NBKT] = N_EDGES;
}

__global__ void k_scan3(const int* __restrict__ ghist, const int* __restrict__ bstart,
                        int* __restrict__ cursors) {
    int j = blockIdx.x * 256 + threadIdx.x;
    if (j >= NBKT) return;
    int run = bstart[j];
    for (int blk = 0; blk < NBLK; ++blk) {
        cursors[blk * NBKT + j] = run;
        run += ghist[blk * NBKT + j];
    }
}

// Scatter edges into dst-bucket-grouped ebuf; packed (src<<9)|(dst&511).
__global__ void k_scatter(const int* e, const int* flag, const int* __restrict__ cursors,
                          unsigned int* __restrict__ ebuf) {
    __shared__ int cur[NBKT];
    const int* c = cursors + blockIdx.x * NBKT;
    for (int i = threadIdx.x; i < NBKT; i += 256) cur[i] = c[i];
    __syncthreads();
    int is64 = *flag;
    long long base = (long long)blockIdx.x * TILE;
    for (int k = threadIdx.x; k < TILE; k += 256) {
        int src = eload(e, is64, base + k);
        int dst = eload(e, is64, (long long)N_EDGES + base + k);
        int pos = atomicAdd(&cur[dst >> BKT_SHIFT], 1);
        ebuf[pos] = ((unsigned)src << BKT_SHIFT) | (unsigned)(dst & BKT_MASK);
    }
}

// Per-bucket counting sort by (src_chunk, dst_local): 2048 bins.
// Emits csr16 (chunk-local src ids), rows4/cnt4 per (chunk,node), dinv.
__launch_bounds__(512)
__global__ void k_sort2(const unsigned int* __restrict__ ebuf, const int* __restrict__ bstart,
                        unsigned short* __restrict__ csr16, int* __restrict__ rows4,
                        int* __restrict__ cnt4, float* __restrict__ dinv) {
    __shared__ int hist[NCHUNK * BKT_SZ];   // 8 KB
    __shared__ int cur[NCHUNK * BKT_SZ];    // 8 KB
    __shared__ int wsum[8];
    int b = blockIdx.x;
    int s0 = bstart[b], e0 = bstart[b + 1];
    int t = threadIdx.x;
#pragma unroll
    for (int i = 0; i < NCHUNK; ++i) hist[i * 512 + t] = 0;
    __syncthreads();
    for (int i = s0 + t; i < e0; i += 512) {
        unsigned v = ebuf[i];
        int src = (int)(v >> BKT_SHIFT);
        int c = src / CBASE;
        atomicAdd(&hist[c * 512 + (v & BKT_MASK)], 1);
    }
    __syncthreads();
    // block-wide exclusive scan over 2048 bins; thread t owns bins 4t..4t+3
    int c0 = hist[4 * t + 0], c1 = hist[4 * t + 1], c2 = hist[4 * t + 2], c3 = hist[4 * t + 3];
    int ssum = c0 + c1 + c2 + c3;
    {
        int lane = t & 63, w = t >> 6;
        int p = ssum;
#pragma unroll
        for (int off = 1; off < 64; off <<= 1) {
            int u = __shfl_up(p, off, 64);
            if (lane >= off) p += u;
        }
        if (lane == 63) wsum[w] = p;
        __syncthreads();
        int woff = 0;
        for (int k = 0; k < w; ++k) woff += wsum[k];
        int excl = woff + p - ssum;          // exclusive prefix of ssum
        int e0b = s0 + excl;
        int e1b = e0b + c0, e2b = e1b + c1, e3b = e2b + c2;
        cur[4 * t + 0] = e0b; cur[4 * t + 1] = e1b;
        cur[4 * t + 2] = e2b; cur[4 * t + 3] = e3b;
        // rows4/cnt4 for the 4 bins
        int starts[4] = {e0b, e1b, e2b, e3b};
        int cnts[4]   = {c0, c1, c2, c3};
#pragma unroll
        for (int i = 0; i < 4; ++i) {
            int bin = 4 * t + i;
            int c = bin >> 9, dl = bin & BKT_MASK;
            int node = b * BKT_SZ + dl;
            if (node < N_NODES) {
                rows4[c * N_NODES + node] = starts[i];
                cnt4[c * N_NODES + node]  = cnts[i];
            }
        }
    }
    __syncthreads();
    // dinv: total degree per node
    {
        int node = b * BKT_SZ + t;
        if (node < N_NODES) {
            int deg = hist[t] + hist[512 + t] + hist[1024 + t] + hist[1536 + t];
            dinv[node] = rsqrtf((float)(deg + 1));
        }
    }
    for (int i = s0 + t; i < e0; i += 512) {
        unsigned v = ebuf[i];
        int src = (int)(v >> BKT_SHIFT);
        int c = src / CBASE;
        int pos = atomicAdd(&cur[c * 512 + (v & BKT_MASK)], 1);
        csr16[pos] = (unsigned short)(src - c * CBASE);
    }
}

// hs[i][c] = dinv[i] * sum_k x[i][k] * W1[k][c]
__launch_bounds__(256)
__global__ void k_gemm1(const float* __restrict__ x, const float* __restrict__ W1,
                        const float* __restrict__ dinv, float* __restrict__ hs) {
    __shared__ float w[IN_CH * HID];
    __shared__ float xs[8 * IN_CH];
    for (int i = threadIdx.x; i < IN_CH * HID; i += 256) w[i] = W1[i];
    const float4* xb = (const float4*)(x + (size_t)blockIdx.x * 8 * IN_CH);
    ((float4*)xs)[threadIdx.x] = xb[threadIdx.x];
    __syncthreads();
    int lane = threadIdx.x & 31, hw = threadIdx.x >> 5;
    int node = blockIdx.x * 8 + hw;
    const float* xr = xs + hw * IN_CH;
    float acc = 0.f;
#pragma unroll
    for (int k = 0; k < IN_CH; ++k) acc += xr[k] * w[k * HID + lane];
    hs[(size_t)node * HID + lane] = acc * dinv[node];
}

// One source-chunk accumulation pass (used by both convs).
__launch_bounds__(256)
__global__ void k_agg_pass(const float* __restrict__ feat, float* __restrict__ acc,
                           const unsigned short* __restrict__ csr16,
                           const int* __restrict__ rows4p, const int* __restrict__ cnt4p,
                           int cbase, int first) {
    int lane = threadIdx.x & 31, hw = threadIdx.x >> 5;
    int node = blockIdx.x * 8 + hw;
    float a = first ? feat[(size_t)node * HID + lane]      // self loop
                    : acc[(size_t)node * HID + lane];
    int start = rows4p[node], len = cnt4p[node];
    const unsigned short* cs = csr16 + start;
    int j = 0;
    for (; j + 8 <= len; j += 8) {
        int t0 = cbase + cs[j + 0], t1 = cbase + cs[j + 1];
        int t2 = cbase + cs[j + 2], t3 = cbase + cs[j + 3];
        int t4 = cbase + cs[j + 4], t5 = cbase + cs[j + 5];
        int t6 = cbase + cs[j + 6], t7 = cbase + cs[j + 7];
        float f0 = feat[(size_t)t0 * HID + lane];
        float f1 = feat[(size_t)t1 * HID + lane];
        float f2 = feat[(size_t)t2 * HID + lane];
        float f3 = feat[(size_t)t3 * HID + lane];
        float f4 = feat[(size_t)t4 * HID + lane];
        float f5 = feat[(size_t)t5 * HID + lane];
        float f6 = feat[(size_t)t6 * HID + lane];
        float f7 = feat[(size_t)t7 * HID + lane];
        a += ((f0 + f1) + (f2 + f3)) + ((f4 + f5) + (f6 + f7));
    }
    for (; j < len; ++j) a += feat[(size_t)(cbase + cs[j]) * HID + lane];
    acc[(size_t)node * HID + lane] = a;
}

// Final chunk pass of conv1 + relu + fused W2 GEMM. acc and hs2 are the SAME buffer.
__launch_bounds__(256)
__global__ void k_agg1_final(const float* __restrict__ hs, float* __restrict__ acc,
                             const unsigned short* __restrict__ csr16,
                             const int* __restrict__ rows4p, const int* __restrict__ cnt4p,
                             int cbase, const float* __restrict__ dinv,
                             const float* __restrict__ b1, const float* __restrict__ W2) {
    __shared__ float w2[HID * HID];
    __shared__ float h1s[8][HID];
    for (int i = threadIdx.x; i < HID * HID; i += 256) w2[i] = W2[i];
    int lane = threadIdx.x & 31, hw = threadIdx.x >> 5;
    int node = blockIdx.x * 8 + hw;
    float a = acc[(size_t)node * HID + lane];
    int start = rows4p[node], len = cnt4p[node];
    const unsigned short* cs = csr16 + start;
    int j = 0;
    for (; j + 8 <= len; j += 8) {
        int t0 = cbase + cs[j + 0], t1 = cbase + cs[j + 1];
        int t2 = cbase + cs[j + 2], t3 = cbase + cs[j + 3];
        int t4 = cbase + cs[j + 4], t5 = cbase + cs[j + 5];
        int t6 = cbase + cs[j + 6], t7 = cbase + cs[j + 7];
        float f0 = hs[(size_t)t0 * HID + lane];
        float f1 = hs[(size_t)t1 * HID + lane];
        float f2 = hs[(size_t)t2 * HID + lane];
        float f3 = hs[(size_t)t3 * HID + lane];
        float f4 = hs[(size_t)t4 * HID + lane];
        float f5 = hs[(size_t)t5 * HID + lane];
        float f6 = hs[(size_t)t6 * HID + lane];
        float f7 = hs[(size_t)t7 * HID + lane];
        a += ((f0 + f1) + (f2 + f3)) + ((f4 + f5) + (f6 + f7));
    }
    for (; j < len; ++j) a += hs[(size_t)(cbase + cs[j]) * HID + lane];
    float dv = dinv[node];
    h1s[hw][lane] = fmaxf(a * dv + b1[lane], 0.f);
    __syncthreads();
    float g = 0.f;
#pragma unroll
    for (int k = 0; k < HID; ++k) g += h1s[hw][k] * w2[k * HID + lane];
    acc[(size_t)node * HID + lane] = g * dv;     // hs2
}

// Final chunk pass of conv2 + relu + fused MLP head.
__launch_bounds__(256)
__global__ void k_agg2_final(const float* __restrict__ hs2, const float* __restrict__ acc,
                             const unsigned short* __restrict__ csr16,
                             const int* __restrict__ rows4p, const int* __restrict__ cnt4p,
                             int cbase, const float* __restrict__ dinv,
                             const float* __restrict__ b2,
                             const float* __restrict__ Wl1, const float* __restrict__ bl1,
                             const float* __restrict__ Wl2, const float* __restrict__ bl2,
                             float* __restrict__ out) {
    __shared__ float wl1[HID * HID];
    __shared__ float h2s[8][HID];
    for (int i = threadIdx.x; i < HID * HID; i += 256) wl1[i] = Wl1[i];
    int lane = threadIdx.x & 31, hw = threadIdx.x >> 5;
    int node = blockIdx.x * 8 + hw;
    float a = acc[(size_t)node * HID + lane];
    int start = rows4p[node], len = cnt4p[node];
    const unsigned short* cs = csr16 + start;
    int j = 0;
    for (; j + 8 <= len; j += 8) {
        int t0 = cbase + cs[j + 0], t1 = cbase + cs[j + 1];
        int t2 = cbase + cs[j + 2], t3 = cbase + cs[j + 3];
        int t4 = cbase + cs[j + 4], t5 = cbase + cs[j + 5];
        int t6 = cbase + cs[j + 6], t7 = cbase + cs[j + 7];
        float f0 = hs2[(size_t)t0 * HID + lane];
        float f1 = hs2[(size_t)t1 * HID + lane];
        float f2 = hs2[(size_t)t2 * HID + lane];
        float f3 = hs2[(size_t)t3 * HID + lane];
        float f4 = hs2[(size_t)t4 * HID + lane];
        float f5 = hs2[(size_t)t5 * HID + lane];
        float f6 = hs2[(size_t)t6 * HID + lane];
        float f7 = hs2[(size_t)t7 * HID + lane];
        a += ((f0 + f1) + (f2 + f3)) + ((f4 + f5) + (f6 + f7));
    }
    for (; j < len; ++j) a += hs2[(size_t)(cbase + cs[j]) * HID + lane];
    float h2 = fmaxf(a * dinv[node] + b2[lane], 0.f);
    h2s[hw][lane] = h2;
    __syncthreads();
    float g = bl1[lane];
#pragma unroll
    for (int k = 0; k < HID; ++k) g += h2s[hw][k] * wl1[k * HID + lane];
    float o = fmaxf(g, 0.f) * Wl2[lane];
#pragma unroll
    for (int off = 16; off; off >>= 1) o += __shfl_down(o, off, 32);
    if (lane == 0) out[node] = o + *bl2;
}

extern "C" void kernel_launch(void* const* d_in, const int* in_sizes, int n_in,
                              void* d_out, int out_size, void* d_ws, size_t ws_size,
                              hipStream_t stream) {
    const float* x   = (const float*)d_in[0];
    const int*   e   = (const int*)d_in[1];
    const float* W1  = (const float*)d_in[2];
    const float* b1  = (const float*)d_in[3];
    const float* W2  = (const float*)d_in[4];
    const float* b2  = (const float*)d_in[5];
    const float* Wl1 = (const float*)d_in[6];
    const float* bl1 = (const float*)d_in[7];
    const float* Wl2 = (const float*)d_in[8];
    const float* bl2 = (const float*)d_in[9];
    float* out = (float*)d_out;

    char* w = (char*)d_ws;
    unsigned int*   ebuf    = (unsigned int*)(w + O_EBUF);
    float*          hs      = (float*)(w + O_HS);
    float*          hs2     = (float*)(w + O_HS2);   // also conv1 acc
    int*            ghist   = (int*)(w + O_GH);
    int*            cursors = (int*)(w + O_CUR);
    unsigned short* csr16   = (unsigned short*)(w + O_CSR);
    int*            rows4   = (int*)(w + O_ROWS4);
    int*            cnt4    = (int*)(w + O_CNT4);
    float*          dinv    = (float*)(w + O_DINV);
    int*            bstart  = (int*)(w + O_BST);
    int*            btot    = (int*)(w + O_BTOT);
    int*            flag    = (int*)(w + O_FLAG);

    const int NB_NODE = N_NODES / 8;          // 12500 exact

    k_detect<<<1, 256, 0, stream>>>((const unsigned int*)e, flag);
    k_hist<<<NBLK, 256, 0, stream>>>(e, flag, ghist);
    k_scan1<<<1, 256, 0, stream>>>(ghist, btot);
    k_scan2<<<1, 1024, 0, stream>>>(btot, bstart);
    k_scan3<<<1, 256, 0, stream>>>(ghist, bstart, cursors);
    k_scatter<<<NBLK, 256, 0, stream>>>(e, flag, cursors, ebuf);
    k_sort2<<<NBKT, 512, 0, stream>>>(ebuf, bstart, csr16, rows4, cnt4, dinv);

    k_gemm1<<<NB_NODE, 256, 0, stream>>>(x, W1, dinv, hs);

    // conv1: 3 accumulate passes + final (acc lives in hs2 region)
    for (int p = 0; p < NCHUNK - 1; ++p)
        k_agg_pass<<<NB_NODE, 256, 0, stream>>>(hs, hs2, csr16,
            rows4 + p * N_NODES, cnt4 + p * N_NODES, p * CBASE, p == 0);
    k_agg1_final<<<NB_NODE, 256, 0, stream>>>(hs, hs2, csr16,
        rows4 + (NCHUNK - 1) * N_NODES, cnt4 + (NCHUNK - 1) * N_NODES,
        (NCHUNK - 1) * CBASE, dinv, b1, W2);

    // conv2: acc lives in hs region (hs is dead after conv1 final)
    for (int p = 0; p < NCHUNK - 1; ++p)
        k_agg_pass<<<NB_NODE, 256, 0, stream>>>(hs2, hs, csr16,
            rows4 + p * N_NODES, cnt4 + p * N_NODES, p * CBASE, p == 0);
    k_agg2_final<<<NB_NODE, 256, 0, stream>>>(hs2, hs, csr16,
        rows4 + (NCHUNK - 1) * N_NODES, cnt4 + (NCHUNK - 1) * N_NODES,
        (NCHUNK - 1) * CBASE, dinv, b2, Wl1, bl1, Wl2, bl2, out);
}